// Round 1
// baseline (604.407 us; speedup 1.0000x reference)
//
#include <hip/hip_runtime.h>

typedef _Float16 half8 __attribute__((ext_vector_type(8)));
typedef float floatx4 __attribute__((ext_vector_type(4)));

#define NS 8
#define CCH 32
#define HK 256
#define PADW 272
#define GRDH_ROWS 288
#define CORR_N (136*136)
#define PCOPY ((size_t)(8*32*272*272))   // elems per parity copy
#define NWG_GEMM 512

// ---- workspace offsets (bytes) ----
#define OFF_NORMSQ   ((size_t)0)
#define OFF_YX       ((size_t)256)
#define OFF_PARTICAL ((size_t)512)                 // 8*17*17 floats
#define OFF_CORR     ((size_t)10240)               // 136*136 floats
#define OFF_E        ((size_t)0x100000)            // 8*256*256 floats (2 MiB)
#define OFF_CSUMG    ((size_t)0x300000)            // 8*256*256 floats
#define OFF_GRDH     ((size_t)0x500000)            // 8*32*288*256 fp16
#define OFF_SATH     ((size_t)0x2A00000)           // 4 parity copies fp16
#define OFF_PARTIALS ((size_t)0xBB00000)           // 512*136*136 floats

__global__ __launch_bounds__(256) void k_init(float* corr, float* normsq) {
    int t = blockIdx.x * 256 + threadIdx.x;
    if (t < CORR_N) corr[t] = 0.f;
    if (t < 8) normsq[t] = 0.f;
}

__global__ __launch_bounds__(256) void k_grdconv(const float* __restrict__ grd,
                                                 _Float16* __restrict__ grdh,
                                                 float* __restrict__ csumg,
                                                 float* __restrict__ normsq) {
    int Rg = blockIdx.x;           // 0..287 padded row
    int n  = blockIdx.y;
    int j  = threadIdx.x;
    if (Rg < 16 || Rg >= 272) {
        for (int c = 0; c < CCH; ++c)
            grdh[(((size_t)(n*CCH + c))*GRDH_ROWS + Rg)*256 + j] = (_Float16)0.f;
        return;
    }
    int i = Rg - 16;
    float ssq = 0.f, cs = 0.f;
    for (int c = 0; c < CCH; ++c) {
        float v = grd[(((size_t)(n*CCH + c))*256 + i)*256 + j];
        grdh[(((size_t)(n*CCH + c))*GRDH_ROWS + Rg)*256 + j] = (_Float16)v;
        ssq += v*v; cs += v;
    }
    csumg[((size_t)n*256 + i)*256 + j] = cs;
    for (int o = 32; o; o >>= 1) ssq += __shfl_down(ssq, o, 64);
    if ((threadIdx.x & 63) == 0) atomicAdd(&normsq[n], ssq);
}

__global__ __launch_bounds__(256) void k_satconv(const float* __restrict__ sat,
                                                 _Float16* __restrict__ sath,
                                                 float* __restrict__ E) {
    int R = blockIdx.x + 8;        // padded row 8..263 (data rows)
    int m = blockIdx.y;
    int j = threadIdx.x;
    int i = R - 8;
    float es = 0.f;
    for (int c = 0; c < CCH; ++c) {
        float v = sat[(((size_t)(m*CCH + c))*256 + i)*256 + j];
        _Float16 h = (_Float16)v;
        es += v*v;
        size_t rowbase = (((size_t)(m*CCH + c))*PADW + R)*PADW;
#pragma unroll
        for (int p = 0; p < 4; ++p)
            sath[(size_t)p*PCOPY + rowbase + (j + 8 - p)] = h;
        if (j < 16) {
#pragma unroll
            for (int p = 0; p < 4; ++p) {
                int Jz = (j < 8 - p) ? j : 256 + j;   // zero pad slots
                sath[(size_t)p*PCOPY + rowbase + Jz] = (_Float16)0.f;
            }
        }
    }
    E[((size_t)m*256 + i)*256 + j] = es;
}

__global__ __launch_bounds__(256) void k_gemm(const _Float16* __restrict__ grdh,
                                              const _Float16* __restrict__ sath,
                                              float* __restrict__ partials) {
    const int wgid = blockIdx.x;       // 0..511
    const int c    = wgid >> 4;        // 0..31
    const int band = wgid & 15;
    const int r0   = 8 + band * 16;
    const int tid  = threadIdx.x;
    const int wave = tid >> 6, lane = tid & 63;
    const int wr = wave >> 1, wc = wave & 1;
    const int lrow = lane & 15, lk = lane >> 4;

    int nA[5], dyA[5], mB[5], pB[5], qB[5];
#pragma unroll
    for (int a = 0; a < 5; ++a) {
        int R = (wr*5 + a)*16 + lrow; if (R > 135) R = 135;
        nA[a] = R / 17; dyA[a] = R % 17;
    }
#pragma unroll
    for (int b = 0; b < 5; ++b) {
        int C = (wc*5 + b)*16 + lrow; if (C > 135) C = 135;
        mB[b] = C / 17;
        int dx = C % 17;
        pB[b] = dx & 3; qB[b] = dx & ~3;
    }

    floatx4 acc[5][5] = {};

    const _Float16* pa[5];
    const _Float16* pb[5];
#pragma unroll
    for (int a = 0; a < 5; ++a)
        pa[a] = grdh + ((((size_t)(nA[a]*CCH + c))*GRDH_ROWS + (r0 + 16 - dyA[a]))*256 + lk*8);
#pragma unroll
    for (int b = 0; b < 5; ++b)
        pb[b] = sath + ((size_t)pB[b]*PCOPY +
                        (((size_t)(mB[b]*CCH + c))*PADW + r0)*PADW + lk*8 + qB[b]);

    for (int r = 0; r < 16; ++r) {
#pragma unroll
        for (int ch = 0; ch < 8; ++ch) {
            half8 A[5], B[5];
#pragma unroll
            for (int a = 0; a < 5; ++a)
                A[a] = *(const half8*)(pa[a] + ch*32);
#pragma unroll
            for (int b = 0; b < 5; ++b) {
                union { unsigned long long u[2]; half8 h; } U;
                U.u[0] = *(const unsigned long long*)(pb[b] + ch*32);
                U.u[1] = *(const unsigned long long*)(pb[b] + ch*32 + 4);
                B[b] = U.h;
            }
#pragma unroll
            for (int a = 0; a < 5; ++a)
#pragma unroll
                for (int b = 0; b < 5; ++b)
                    acc[a][b] = __builtin_amdgcn_mfma_f32_16x16x32_f16(A[a], B[b], acc[a][b], 0, 0, 0);
        }
#pragma unroll
        for (int a = 0; a < 5; ++a) pa[a] += 256;
#pragma unroll
        for (int b = 0; b < 5; ++b) pb[b] += PADW;
    }

    float* myp = partials + (size_t)wgid * CORR_N;
#pragma unroll
    for (int a = 0; a < 5; ++a) {
        int rowb = (wr*5 + a)*16 + lk*4;
#pragma unroll
        for (int b = 0; b < 5; ++b) {
            int colg = (wc*5 + b)*16 + lrow;
            if (colg < 136) {
#pragma unroll
                for (int v = 0; v < 4; ++v) {
                    int rowg = rowb + v;
                    if (rowg < 136) myp[rowg*136 + colg] = acc[a][b][v];
                }
            }
        }
    }
}

__global__ __launch_bounds__(256) void k_reduce(const float* __restrict__ partials,
                                                float* __restrict__ corr) {
    int t = blockIdx.x * 256 + threadIdx.x;
    if (t >= CORR_N) return;
    int w0 = blockIdx.y * 64;
    float s = 0.f;
    for (int w = w0; w < w0 + 64; ++w) s += partials[(size_t)w*CORR_N + t];
    atomicAdd(&corr[t], s);
}

__global__ __launch_bounds__(256) void k_part(const float* __restrict__ E,
                                              float* __restrict__ partical) {
    int dy = blockIdx.x;   // 0..16
    int m  = blockIdx.y;
    int j  = threadIdx.x;
    int lo = dy - 8; if (lo < 0) lo = 0;
    int hi = dy + 248; if (hi > 256) hi = 256;
    float s = 0.f;
    for (int i = lo; i < hi; ++i) s += E[((size_t)m*256 + i)*256 + j];
    __shared__ float sh[256];
    sh[j] = s;
    __syncthreads();
    if (j < 17) {
        int lo2 = j - 8; if (lo2 < 0) lo2 = 0;
        int hi2 = j + 248; if (hi2 > 256) hi2 = 256;
        float t = 0.f;
        for (int x = lo2; x < hi2; ++x) t += sh[x];
        partical[(m*17 + dy)*17 + j] = t;
    }
}

__global__ __launch_bounds__(64) void k_sim(const float* __restrict__ corr,
                                            const float* __restrict__ partical,
                                            const float* __restrict__ normsq,
                                            float* __restrict__ out,
                                            int* __restrict__ yx) {
    int m = blockIdx.x >> 3, n = blockIdx.x & 7;
    int lane = threadIdx.x;
    float Ng = sqrtf(normsq[n]);
    float bv = -1e30f; int bpos = 0;
    for (int t = 0; t < 5; ++t) {
        int pos = t*64 + lane;
        if (pos < 289) {
            int dy = pos / 17, dx = pos % 17;
            float denom = fmaxf(Ng * sqrtf(partical[(m*17 + dy)*17 + dx]), 1e-12f);
            float val = corr[(n*17 + dy)*136 + (m*17 + dx)] / denom;
            if (val > bv) { bv = val; bpos = pos; }  // strict > keeps first index
        }
    }
    for (int o = 32; o; o >>= 1) {
        float ov = __shfl_xor(bv, o, 64);
        int   op = __shfl_xor(bpos, o, 64);
        if (ov > bv || (ov == bv && op < bpos)) { bv = ov; bpos = op; }
    }
    if (lane == 0) {
        out[m*8 + n] = bv;
        if (m == n) yx[m] = bpos;
    }
}

__global__ __launch_bounds__(256) void k_mask(const float* __restrict__ csumg,
                                              const float* __restrict__ normsq,
                                              const int* __restrict__ yx,
                                              float* __restrict__ out) {
    int i = blockIdx.x, m = blockIdx.y, j = threadIdx.x;
    int pos = yx[m];
    int y = pos / 17, x = pos % 17;
    float Ng = sqrtf(normsq[m]);
    int a = i + 8 - y, b = j + 8 - x;
    float val = 0.f;
    if (a >= 0 && a < 256 && b >= 0 && b < 256)
        val = (fabsf(csumg[((size_t)m*256 + a)*256 + b]) > 1e-6f*Ng) ? 1.f : 0.f;
    out[64 + ((size_t)m*256 + i)*256 + j] = val;
}

extern "C" void kernel_launch(void* const* d_in, const int* in_sizes, int n_in,
                              void* d_out, int out_size, void* d_ws, size_t ws_size,
                              hipStream_t stream) {
    const float* grd = (const float*)d_in[0];
    const float* sat = (const float*)d_in[1];
    float* out = (float*)d_out;
    char* ws = (char*)d_ws;

    float*    normsq   = (float*)(ws + OFF_NORMSQ);
    int*      yx       = (int*)  (ws + OFF_YX);
    float*    partical = (float*)(ws + OFF_PARTICAL);
    float*    corr     = (float*)(ws + OFF_CORR);
    float*    E        = (float*)(ws + OFF_E);
    float*    csumg    = (float*)(ws + OFF_CSUMG);
    _Float16* grdh     = (_Float16*)(ws + OFF_GRDH);
    _Float16* sath     = (_Float16*)(ws + OFF_SATH);
    float*    partials = (float*)(ws + OFF_PARTIALS);

    k_init<<<(CORR_N + 255)/256, 256, 0, stream>>>(corr, normsq);
    k_grdconv<<<dim3(288, 8), 256, 0, stream>>>(grd, grdh, csumg, normsq);
    k_satconv<<<dim3(256, 8), 256, 0, stream>>>(sat, sath, E);
    k_gemm<<<NWG_GEMM, 256, 0, stream>>>(grdh, sath, partials);
    k_reduce<<<dim3((CORR_N + 255)/256, 8), 256, 0, stream>>>(partials, corr);
    k_part<<<dim3(17, 8), 256, 0, stream>>>(E, partical);
    k_sim<<<64, 64, 0, stream>>>(corr, partical, normsq, out, yx);
    k_mask<<<dim3(256, 8), 256, 0, stream>>>(csumg, normsq, yx, out);
}

// Round 4
// 512.209 us; speedup vs baseline: 1.1800x; 1.1800x over previous
//
#include <hip/hip_runtime.h>

typedef _Float16 half8 __attribute__((ext_vector_type(8)));
typedef float floatx4 __attribute__((ext_vector_type(4)));

#define NS 8
#define CCH 32
#define PADW 272
#define GRDH_ROWS 288
#define CORR_N (136*136)
#define PCOPY (8*32*272*272)             // elems per parity copy (18,939,904)
#define NWG_GEMM 512

// ---- workspace offsets (bytes) ----
#define OFF_NORMSQ   ((size_t)0)
#define OFF_YX       ((size_t)256)
#define OFF_PARTICAL ((size_t)512)                 // 8*17*17 floats
#define OFF_CORR     ((size_t)10240)               // 136*136 floats
#define OFF_E        ((size_t)0x100000)            // 8*256*256 floats (2 MiB)
#define OFF_CSUMG    ((size_t)0x300000)            // 8*256*256 floats
#define OFF_GRDH     ((size_t)0x500000)            // 8*32*288*256 fp16
#define OFF_SATH     ((size_t)0x2A00000)           // 4 parity copies fp16
#define OFF_PARTIALS ((size_t)0xBB00000)           // 512*136*136 floats

__global__ __launch_bounds__(256) void k_init(float* corr, float* normsq) {
    int t = blockIdx.x * 256 + threadIdx.x;
    if (t < CORR_N) corr[t] = 0.f;
    if (t < 8) normsq[t] = 0.f;
}

// grd -> fp16 padded-row layout + per-sample norm^2 + channel-sum (for mask)
__global__ __launch_bounds__(256) void k_grdconv(const float* __restrict__ grd,
                                                 _Float16* __restrict__ grdh,
                                                 float* __restrict__ csumg,
                                                 float* __restrict__ normsq) {
    int Rg = blockIdx.x;           // 0..287 padded row
    int n  = blockIdx.y;
    int tid = threadIdx.x;
    int ct = tid >> 7;             // 0..1 channel half
    int cp = tid & 127;            // col pair index
    int j0 = cp * 2;
    union HU { _Float16 h; unsigned short u; };

    if (Rg < 16 || Rg >= 272) {
        for (int cc = 0; cc < 16; ++cc) {
            int c = ct * 16 + cc;
            *(ushort2*)(grdh + (((size_t)(n*CCH + c))*GRDH_ROWS + Rg)*256 + j0) =
                make_ushort2(0, 0);
        }
        return;
    }
    int i = Rg - 16;
    float ssq = 0.f, cs0 = 0.f, cs1 = 0.f;
    for (int cc = 0; cc < 16; ++cc) {
        int c = ct * 16 + cc;
        float2 v = *(const float2*)(grd + (((size_t)(n*CCH + c))*256 + i)*256 + j0);
        HU h0, h1; h0.h = (_Float16)v.x; h1.h = (_Float16)v.y;
        *(ushort2*)(grdh + (((size_t)(n*CCH + c))*GRDH_ROWS + Rg)*256 + j0) =
            make_ushort2(h0.u, h1.u);
        ssq += v.x*v.x + v.y*v.y;
        cs0 += v.x; cs1 += v.y;
    }
    __shared__ float sh[2][256];
    sh[ct][j0] = cs0; sh[ct][j0+1] = cs1;
    __syncthreads();
    if (ct == 0) {
        float2 o; o.x = sh[0][j0] + sh[1][j0]; o.y = sh[0][j0+1] + sh[1][j0+1];
        *(float2*)(csumg + ((size_t)n*256 + i)*256 + j0) = o;
    }
    for (int o = 32; o; o >>= 1) ssq += __shfl_down(ssq, o, 64);
    if ((tid & 63) == 0) atomicAdd(&normsq[n], ssq);
}

// sat -> 4 parity-shifted fp16 padded copies (coalesced ushort2 stores via LDS)
// + per-pixel channel energy E
__global__ __launch_bounds__(256) void k_satconv(const float* __restrict__ sat,
                                                 _Float16* __restrict__ sath,
                                                 float* __restrict__ E) {
    int R = blockIdx.x + 8;        // padded row 8..263
    int m = blockIdx.y;
    int tid = threadIdx.x;
    int i = R - 8;
    union HU { _Float16 h; unsigned short u; };

    __shared__ unsigned short lds[276];
    // zero the pad slots once (data slots 8..263 rewritten every c)
    if (tid < 8)  lds[tid] = 0;
    if (tid >= 244) lds[tid + 20] = 0;   // covers 264..275

    int p = tid >> 6;              // parity copy 0..3
    int s = tid & 63;              // slot within copy

    float es = 0.f;
    for (int c = 0; c < CCH; ++c) {
        float v = sat[(((size_t)(m*CCH + c))*256 + i)*256 + tid];
        es += v*v;
        HU h; h.h = (_Float16)v;
        __syncthreads();           // WAR: previous c's readers done
        lds[8 + tid] = h.u;
        __syncthreads();
        size_t rowbase = (size_t)p*PCOPY + (((size_t)(m*CCH + c))*PADW + R)*PADW;
        // ushort2 slot k covers out cols 2k,2k+1; value = lds[2k+p], lds[2k+1+p]
        {
            int k = s;
            *(ushort2*)(sath + rowbase + 2*k) = make_ushort2(lds[2*k+p], lds[2*k+1+p]);
            k = s + 64;
            *(ushort2*)(sath + rowbase + 2*k) = make_ushort2(lds[2*k+p], lds[2*k+1+p]);
            if (s < 8) {
                k = s + 128;
                *(ushort2*)(sath + rowbase + 2*k) = make_ushort2(lds[2*k+p], lds[2*k+1+p]);
            }
        }
    }
    E[((size_t)m*256 + i)*256 + tid] = es;
}

// all-pairs shifted correlation as MFMA GEMM, 2-deep register pipeline
__global__ __launch_bounds__(256, 2) void k_gemm(const _Float16* __restrict__ grdh,
                                                 const _Float16* __restrict__ sath,
                                                 float* __restrict__ partials) {
    const int wgid = blockIdx.x;       // 0..511
    const int c    = wgid >> 4;        // 0..31
    const int band = wgid & 15;
    const int r0   = 8 + band * 16;
    const int tid  = threadIdx.x;
    const int wave = tid >> 6, lane = tid & 63;
    const int wr = wave >> 1, wc = wave & 1;
    const int lrow = lane & 15, lk = lane >> 4;

    int offA[5], offB[5];
#pragma unroll
    for (int a = 0; a < 5; ++a) {
        int R = (wr*5 + a)*16 + lrow; if (R > 135) R = 135;
        int n = R / 17, dy = R % 17;
        offA[a] = ((n*CCH + c)*GRDH_ROWS + (r0 + 16 - dy))*256 + lk*8;
    }
#pragma unroll
    for (int b = 0; b < 5; ++b) {
        int C = (wc*5 + b)*16 + lrow; if (C > 135) C = 135;
        int m = C / 17, dx = C % 17;
        offB[b] = (dx & 3)*PCOPY + ((m*CCH + c)*PADW + r0)*PADW + lk*8 + (dx & ~3);
    }

    floatx4 acc[5][5] = {};
    half8 A0[5], B0[5], A1[5], B1[5];

#define LOADF(Ab, Bb, RX, CH) do { \
    _Pragma("unroll") for (int a = 0; a < 5; ++a) \
        Ab[a] = *(const half8*)(grdh + offA[a] + (RX)*256 + (CH)*32); \
    _Pragma("unroll") for (int b = 0; b < 5; ++b) { \
        union { unsigned long long u[2]; half8 h; } U_; \
        U_.u[0] = *(const unsigned long long*)(sath + offB[b] + (RX)*PADW + (CH)*32); \
        U_.u[1] = *(const unsigned long long*)(sath + offB[b] + (RX)*PADW + (CH)*32 + 4); \
        Bb[b] = U_.h; } \
} while (0)

#define MFMAS(Ab, Bb) do { \
    _Pragma("unroll") for (int a = 0; a < 5; ++a) \
    _Pragma("unroll") for (int b = 0; b < 5; ++b) \
        acc[a][b] = __builtin_amdgcn_mfma_f32_16x16x32_f16(Ab[a], Bb[b], acc[a][b], 0, 0, 0); \
} while (0)

    LOADF(A0, B0, 0, 0);
    for (int r = 0; r < 16; ++r) {
        LOADF(A1, B1, 0, 1); MFMAS(A0, B0);
        LOADF(A0, B0, 0, 2); MFMAS(A1, B1);
        LOADF(A1, B1, 0, 3); MFMAS(A0, B0);
        LOADF(A0, B0, 0, 4); MFMAS(A1, B1);
        LOADF(A1, B1, 0, 5); MFMAS(A0, B0);
        LOADF(A0, B0, 0, 6); MFMAS(A1, B1);
        LOADF(A1, B1, 0, 7); MFMAS(A0, B0);
        LOADF(A0, B0, 1, 0); MFMAS(A1, B1);   // prefetch next r (last one discarded)
#pragma unroll
        for (int a = 0; a < 5; ++a) offA[a] += 256;
#pragma unroll
        for (int b = 0; b < 5; ++b) offB[b] += PADW;
    }
#undef LOADF
#undef MFMAS

    float* myp = partials + (size_t)wgid * CORR_N;
#pragma unroll
    for (int a = 0; a < 5; ++a) {
        int rowb = (wr*5 + a)*16 + lk*4;
#pragma unroll
        for (int b = 0; b < 5; ++b) {
            int colg = (wc*5 + b)*16 + lrow;
            if (colg < 136) {
#pragma unroll
                for (int v = 0; v < 4; ++v) {
                    int rowg = rowb + v;
                    if (rowg < 136) myp[rowg*136 + colg] = acc[a][b][v];
                }
            }
        }
    }
}

__global__ __launch_bounds__(256) void k_reduce(const float* __restrict__ partials,
                                                float* __restrict__ corr) {
    int t = blockIdx.x * 256 + threadIdx.x;
    if (t >= CORR_N) return;
    int w0 = blockIdx.y * 64;
    float s = 0.f;
    for (int w = w0; w < w0 + 64; ++w) s += partials[(size_t)w*CORR_N + t];
    atomicAdd(&corr[t], s);
}

__global__ __launch_bounds__(256) void k_part(const float* __restrict__ E,
                                              float* __restrict__ partical) {
    int dy = blockIdx.x;   // 0..16
    int m  = blockIdx.y;
    int j  = threadIdx.x;
    int lo = dy - 8; if (lo < 0) lo = 0;
    int hi = dy + 248; if (hi > 256) hi = 256;
    float s = 0.f;
    for (int i = lo; i < hi; ++i) s += E[((size_t)m*256 + i)*256 + j];
    __shared__ float sh[256];
    sh[j] = s;
    __syncthreads();
    if (j < 17) {
        int lo2 = j - 8; if (lo2 < 0) lo2 = 0;
        int hi2 = j + 248; if (hi2 > 256) hi2 = 256;
        float t = 0.f;
        for (int x = lo2; x < hi2; ++x) t += sh[x];
        partical[(m*17 + dy)*17 + j] = t;
    }
}

__global__ __launch_bounds__(64) void k_sim(const float* __restrict__ corr,
                                            const float* __restrict__ partical,
                                            const float* __restrict__ normsq,
                                            float* __restrict__ out,
                                            int* __restrict__ yx) {
    int m = blockIdx.x >> 3, n = blockIdx.x & 7;
    int lane = threadIdx.x;
    float Ng = sqrtf(normsq[n]);
    float bv = -1e30f; int bpos = 0;
    for (int t = 0; t < 5; ++t) {
        int pos = t*64 + lane;
        if (pos < 289) {
            int dy = pos / 17, dx = pos % 17;
            float denom = fmaxf(Ng * sqrtf(partical[(m*17 + dy)*17 + dx]), 1e-12f);
            float val = corr[(n*17 + dy)*136 + (m*17 + dx)] / denom;
            if (val > bv) { bv = val; bpos = pos; }  // strict > keeps first index
        }
    }
    for (int o = 32; o; o >>= 1) {
        float ov = __shfl_xor(bv, o, 64);
        int   op = __shfl_xor(bpos, o, 64);
        if (ov > bv || (ov == bv && op < bpos)) { bv = ov; bpos = op; }
    }
    if (lane == 0) {
        out[m*8 + n] = bv;
        if (m == n) yx[m] = bpos;
    }
}

__global__ __launch_bounds__(256) void k_mask(const float* __restrict__ csumg,
                                              const float* __restrict__ normsq,
                                              const int* __restrict__ yx,
                                              float* __restrict__ out) {
    int i = blockIdx.x, m = blockIdx.y, j = threadIdx.x;
    int pos = yx[m];
    int y = pos / 17, x = pos % 17;
    float Ng = sqrtf(normsq[m]);
    int a = i + 8 - y, b = j + 8 - x;
    float val = 0.f;
    if (a >= 0 && a < 256 && b >= 0 && b < 256)
        val = (fabsf(csumg[((size_t)m*256 + a)*256 + b]) > 1e-6f*Ng) ? 1.f : 0.f;
    out[64 + ((size_t)m*256 + i)*256 + j] = val;
}

extern "C" void kernel_launch(void* const* d_in, const int* in_sizes, int n_in,
                              void* d_out, int out_size, void* d_ws, size_t ws_size,
                              hipStream_t stream) {
    const float* grd = (const float*)d_in[0];
    const float* sat = (const float*)d_in[1];
    float* out = (float*)d_out;
    char* ws = (char*)d_ws;

    float*    normsq   = (float*)(ws + OFF_NORMSQ);
    int*      yx       = (int*)  (ws + OFF_YX);
    float*    partical = (float*)(ws + OFF_PARTICAL);
    float*    corr     = (float*)(ws + OFF_CORR);
    float*    E        = (float*)(ws + OFF_E);
    float*    csumg    = (float*)(ws + OFF_CSUMG);
    _Float16* grdh     = (_Float16*)(ws + OFF_GRDH);
    _Float16* sath     = (_Float16*)(ws + OFF_SATH);
    float*    partials = (float*)(ws + OFF_PARTIALS);

    k_init<<<(CORR_N + 255)/256, 256, 0, stream>>>(corr, normsq);
    k_grdconv<<<dim3(288, 8), 256, 0, stream>>>(grd, grdh, csumg, normsq);
    k_satconv<<<dim3(256, 8), 256, 0, stream>>>(sat, sath, E);
    k_gemm<<<NWG_GEMM, 256, 0, stream>>>(grdh, sath, partials);
    k_reduce<<<dim3((CORR_N + 255)/256, 8), 256, 0, stream>>>(partials, corr);
    k_part<<<dim3(17, 8), 256, 0, stream>>>(E, partical);
    k_sim<<<64, 64, 0, stream>>>(corr, partical, normsq, out, yx);
    k_mask<<<dim3(256, 8), 256, 0, stream>>>(csumg, normsq, yx, out);
}

// Round 5
// 425.756 us; speedup vs baseline: 1.4196x; 1.2031x over previous
//
#include <hip/hip_runtime.h>

typedef _Float16 half8 __attribute__((ext_vector_type(8)));
typedef _Float16 half4 __attribute__((ext_vector_type(4)));
typedef float floatx4 __attribute__((ext_vector_type(4)));

#define NS 8
#define CCH 32
#define PADW 272
#define GRDH_ROWS 288
#define CORR_N (136*136)
#define PCOPY (8*32*272*272)             // elems per parity copy (18,939,904)
#define NWG_GEMM 512

#define LDSA_BYTES 81920                 // 160 rows x 256 halfs
#define LDSB_BYTES 69632                 // 128 rows x 272 halfs
#define LDS_TOTAL  (LDSA_BYTES + LDSB_BYTES)   // 151552 <= 160 KiB

// ---- workspace offsets (bytes) ----
#define OFF_NORMSQ   ((size_t)0)
#define OFF_YX       ((size_t)256)
#define OFF_PARTICAL ((size_t)512)                 // 8*17*17 floats
#define OFF_CORR     ((size_t)10240)               // 136*136 floats
#define OFF_E        ((size_t)0x100000)            // 8*256*256 floats (2 MiB)
#define OFF_CSUMG    ((size_t)0x300000)            // 8*256*256 floats
#define OFF_GRDH     ((size_t)0x500000)            // 8*32*288*256 fp16
#define OFF_SATH     ((size_t)0x2A00000)           // 4 parity copies fp16
#define OFF_PARTIALS ((size_t)0xBB00000)           // 512*136*136 floats

__global__ __launch_bounds__(256) void k_init(float* corr, float* normsq) {
    int t = blockIdx.x * 256 + threadIdx.x;
    if (t < CORR_N) corr[t] = 0.f;
    if (t < 8) normsq[t] = 0.f;
}

// grd -> fp16 padded-row layout + per-sample norm^2 + channel-sum (for mask)
__global__ __launch_bounds__(256) void k_grdconv(const float* __restrict__ grd,
                                                 _Float16* __restrict__ grdh,
                                                 float* __restrict__ csumg,
                                                 float* __restrict__ normsq) {
    int Rg = blockIdx.x;           // 0..287 padded row
    int n  = blockIdx.y;
    int tid = threadIdx.x;
    int ct = tid >> 7;             // 0..1 channel half
    int cp = tid & 127;            // col pair index
    int j0 = cp * 2;
    union HU { _Float16 h; unsigned short u; };

    if (Rg < 16 || Rg >= 272) {
        for (int cc = 0; cc < 16; ++cc) {
            int c = ct * 16 + cc;
            *(ushort2*)(grdh + (((size_t)(n*CCH + c))*GRDH_ROWS + Rg)*256 + j0) =
                make_ushort2(0, 0);
        }
        return;
    }
    int i = Rg - 16;
    float ssq = 0.f, cs0 = 0.f, cs1 = 0.f;
    for (int cc = 0; cc < 16; ++cc) {
        int c = ct * 16 + cc;
        float2 v = *(const float2*)(grd + (((size_t)(n*CCH + c))*256 + i)*256 + j0);
        HU h0, h1; h0.h = (_Float16)v.x; h1.h = (_Float16)v.y;
        *(ushort2*)(grdh + (((size_t)(n*CCH + c))*GRDH_ROWS + Rg)*256 + j0) =
            make_ushort2(h0.u, h1.u);
        ssq += v.x*v.x + v.y*v.y;
        cs0 += v.x; cs1 += v.y;
    }
    __shared__ float sh[2][256];
    sh[ct][j0] = cs0; sh[ct][j0+1] = cs1;
    __syncthreads();
    if (ct == 0) {
        float2 o; o.x = sh[0][j0] + sh[1][j0]; o.y = sh[0][j0+1] + sh[1][j0+1];
        *(float2*)(csumg + ((size_t)n*256 + i)*256 + j0) = o;
    }
    for (int o = 32; o; o >>= 1) ssq += __shfl_down(ssq, o, 64);
    if ((tid & 63) == 0) atomicAdd(&normsq[n], ssq);
}

// sat -> 4 parity-shifted fp16 padded copies (coalesced ushort2 stores via LDS)
// + per-pixel channel energy E
__global__ __launch_bounds__(256) void k_satconv(const float* __restrict__ sat,
                                                 _Float16* __restrict__ sath,
                                                 float* __restrict__ E) {
    int R = blockIdx.x + 8;        // padded row 8..263
    int m = blockIdx.y;
    int tid = threadIdx.x;
    int i = R - 8;
    union HU { _Float16 h; unsigned short u; };

    __shared__ unsigned short lds[276];
    // zero the pad slots once (data slots 8..263 rewritten every c)
    if (tid < 8)  lds[tid] = 0;
    if (tid >= 244) lds[tid + 20] = 0;   // covers 264..275

    int p = tid >> 6;              // parity copy 0..3
    int s = tid & 63;              // slot within copy

    float es = 0.f;
    for (int c = 0; c < CCH; ++c) {
        float v = sat[(((size_t)(m*CCH + c))*256 + i)*256 + tid];
        es += v*v;
        HU h; h.h = (_Float16)v;
        __syncthreads();           // WAR: previous c's readers done
        lds[8 + tid] = h.u;
        __syncthreads();
        size_t rowbase = (size_t)p*PCOPY + (((size_t)(m*CCH + c))*PADW + R)*PADW;
        // ushort2 slot k covers out cols 2k,2k+1; value = lds[2k+p], lds[2k+1+p]
        {
            int k = s;
            *(ushort2*)(sath + rowbase + 2*k) = make_ushort2(lds[2*k+p], lds[2*k+1+p]);
            k = s + 64;
            *(ushort2*)(sath + rowbase + 2*k) = make_ushort2(lds[2*k+p], lds[2*k+1+p]);
            if (s < 8) {
                k = s + 128;
                *(ushort2*)(sath + rowbase + 2*k) = make_ushort2(lds[2*k+p], lds[2*k+1+p]);
            }
        }
    }
    E[((size_t)m*256 + i)*256 + tid] = es;
}

// all-pairs shifted correlation as MFMA GEMM, LDS-staged via global_load_lds.
// WG = (channel-group of 4) x (band of 4 sat rows); 512 WGs total.
// LDS A: [160 rows = 8n x 20 window][256 halfs], XOR-swizzled 16B chunks.
// LDS B: [128 rows = 4parity x 4r x 8m][272 halfs], linear.
__global__ __launch_bounds__(256) void k_gemm(const _Float16* __restrict__ grdh,
                                              const _Float16* __restrict__ sath,
                                              float* __restrict__ partials) {
    extern __shared__ char smem[];
    _Float16* ldsA = (_Float16*)smem;
    _Float16* ldsB = (_Float16*)(smem + LDSA_BYTES);

    const int wgid = blockIdx.x;       // 0..511
    const int cg   = wgid & 7;         // channel group (4 channels each)
    const int band = wgid >> 3;        // 0..63
    const int r0   = 8 + band * 4;
    const int tid  = threadIdx.x;
    const int wave = tid >> 6, lane = tid & 63;
    const int wr = wave >> 1, wc = wave & 1;
    const int lrow = lane & 15, lk = lane >> 4;

    int sBaseA[5];                     // LDS A row base (n*20 + 16 - dy)
    int baseB[5];                      // LDS B byte base
#pragma unroll
    for (int a = 0; a < 5; ++a) {
        int v = (wr*5 + a)*16 + lrow; if (v > 135) v = 135;
        int n = v / 17, dy = v % 17;
        sBaseA[a] = n*20 + 16 - dy;
    }
#pragma unroll
    for (int b = 0; b < 5; ++b) {
        int C = (wc*5 + b)*16 + lrow; if (C > 135) C = 135;
        int m = C / 17, dx = C % 17;
        baseB[b] = ((dx & 3)*32 + m)*544 + ((dx & ~3) + lk*8)*2;
    }

    floatx4 acc[5][5] = {};
    union BU { half8 v; half4 h[2]; };
    half8 A0[5], A1[5];
    BU B0[5], B1[5];

#define LOADPH(Ax, Bx, PH) do { \
    const int r_ = (PH) >> 3, ch_ = (PH) & 7; \
    _Pragma("unroll") for (int a = 0; a < 5; ++a) { \
        int s_ = sBaseA[a] + r_; \
        int byte_ = (s_ << 9) + ((((ch_*4) + lk) ^ (s_ & 7)) << 4); \
        Ax[a] = *(const half8*)((const char*)ldsA + byte_); } \
    _Pragma("unroll") for (int b = 0; b < 5; ++b) { \
        int off_ = baseB[b] + r_*4352 + ch_*64; \
        Bx[b].h[0] = *(const half4*)((const char*)ldsB + off_); \
        Bx[b].h[1] = *(const half4*)((const char*)ldsB + off_ + 8); } \
} while (0)

#define MFMAS(Ax, Bx) do { \
    _Pragma("unroll") for (int a = 0; a < 5; ++a) \
    _Pragma("unroll") for (int b = 0; b < 5; ++b) \
        acc[a][b] = __builtin_amdgcn_mfma_f32_16x16x32_f16(Ax[a], Bx[b].v, acc[a][b], 0, 0, 0); \
} while (0)

    for (int g = 0; g < 4; ++g) {
        int cc = cg*4 + g;
        __syncthreads();               // prev iteration's readers done
        // stage A: 5120 x 16B chunks (20 per thread), XOR pre-swizzled source
#pragma unroll
        for (int it = 0; it < 20; ++it) {
            int chunk = it*256 + tid;
            int s = chunk >> 5, k = chunk & 31;
            int n = s / 20, w = s - n*20;
            const _Float16* src = grdh +
                ((((size_t)(n*CCH + cc))*GRDH_ROWS + (r0 + w)) << 8) + ((k ^ (s & 7)) << 3);
            __builtin_amdgcn_global_load_lds(src, ldsA + chunk*8, 16, 0, 0);
        }
        // stage B: 4352 x 16B chunks (17 per thread), linear
#pragma unroll
        for (int it = 0; it < 17; ++it) {
            int chunk = it*256 + tid;
            int row = chunk / 34, k = chunk - row*34;
            int p = row >> 5, rr = (row >> 3) & 3, m = row & 7;
            const _Float16* src = sath + (size_t)p*PCOPY +
                (((size_t)(m*CCH + cc))*PADW + (r0 + rr))*PADW + k*8;
            __builtin_amdgcn_global_load_lds(src, ldsB + chunk*8, 16, 0, 0);
        }
        asm volatile("s_waitcnt vmcnt(0)" ::: "memory");
        __syncthreads();               // all staging visible

        LOADPH(A0, B0, 0);
#pragma unroll
        for (int ph = 0; ph < 32; ++ph) {
            if ((ph & 1) == 0) {
                if (ph < 31) LOADPH(A1, B1, ph + 1);
                MFMAS(A0, B0);
            } else {
                if (ph < 31) LOADPH(A0, B0, ph + 1);
                MFMAS(A1, B1);
            }
        }
    }
#undef LOADPH
#undef MFMAS

    float* myp = partials + (size_t)wgid * CORR_N;
#pragma unroll
    for (int a = 0; a < 5; ++a) {
        int rowb = (wr*5 + a)*16 + lk*4;
#pragma unroll
        for (int b = 0; b < 5; ++b) {
            int colg = (wc*5 + b)*16 + lrow;
            if (colg < 136) {
#pragma unroll
                for (int v = 0; v < 4; ++v) {
                    int rowg = rowb + v;
                    if (rowg < 136) myp[rowg*136 + colg] = acc[a][b][v];
                }
            }
        }
    }
}

__global__ __launch_bounds__(256) void k_reduce(const float* __restrict__ partials,
                                                float* __restrict__ corr) {
    int t = blockIdx.x * 256 + threadIdx.x;
    if (t >= CORR_N) return;
    int w0 = blockIdx.y * 64;
    float s = 0.f;
    for (int w = w0; w < w0 + 64; ++w) s += partials[(size_t)w*CORR_N + t];
    atomicAdd(&corr[t], s);
}

__global__ __launch_bounds__(256) void k_part(const float* __restrict__ E,
                                              float* __restrict__ partical) {
    int dy = blockIdx.x;   // 0..16
    int m  = blockIdx.y;
    int j  = threadIdx.x;
    int lo = dy - 8; if (lo < 0) lo = 0;
    int hi = dy + 248; if (hi > 256) hi = 256;
    float s = 0.f;
    for (int i = lo; i < hi; ++i) s += E[((size_t)m*256 + i)*256 + j];
    __shared__ float sh[256];
    sh[j] = s;
    __syncthreads();
    if (j < 17) {
        int lo2 = j - 8; if (lo2 < 0) lo2 = 0;
        int hi2 = j + 248; if (hi2 > 256) hi2 = 256;
        float t = 0.f;
        for (int x = lo2; x < hi2; ++x) t += sh[x];
        partical[(m*17 + dy)*17 + j] = t;
    }
}

__global__ __launch_bounds__(64) void k_sim(const float* __restrict__ corr,
                                            const float* __restrict__ partical,
                                            const float* __restrict__ normsq,
                                            float* __restrict__ out,
                                            int* __restrict__ yx) {
    int m = blockIdx.x >> 3, n = blockIdx.x & 7;
    int lane = threadIdx.x;
    float Ng = sqrtf(normsq[n]);
    float bv = -1e30f; int bpos = 0;
    for (int t = 0; t < 5; ++t) {
        int pos = t*64 + lane;
        if (pos < 289) {
            int dy = pos / 17, dx = pos % 17;
            float denom = fmaxf(Ng * sqrtf(partical[(m*17 + dy)*17 + dx]), 1e-12f);
            float val = corr[(n*17 + dy)*136 + (m*17 + dx)] / denom;
            if (val > bv) { bv = val; bpos = pos; }  // strict > keeps first index
        }
    }
    for (int o = 32; o; o >>= 1) {
        float ov = __shfl_xor(bv, o, 64);
        int   op = __shfl_xor(bpos, o, 64);
        if (ov > bv || (ov == bv && op < bpos)) { bv = ov; bpos = op; }
    }
    if (lane == 0) {
        out[m*8 + n] = bv;
        if (m == n) yx[m] = bpos;
    }
}

__global__ __launch_bounds__(256) void k_mask(const float* __restrict__ csumg,
                                              const float* __restrict__ normsq,
                                              const int* __restrict__ yx,
                                              float* __restrict__ out) {
    int i = blockIdx.x, m = blockIdx.y, j = threadIdx.x;
    int pos = yx[m];
    int y = pos / 17, x = pos % 17;
    float Ng = sqrtf(normsq[m]);
    int a = i + 8 - y, b = j + 8 - x;
    float val = 0.f;
    if (a >= 0 && a < 256 && b >= 0 && b < 256)
        val = (fabsf(csumg[((size_t)m*256 + a)*256 + b]) > 1e-6f*Ng) ? 1.f : 0.f;
    out[64 + ((size_t)m*256 + i)*256 + j] = val;
}

extern "C" void kernel_launch(void* const* d_in, const int* in_sizes, int n_in,
                              void* d_out, int out_size, void* d_ws, size_t ws_size,
                              hipStream_t stream) {
    const float* grd = (const float*)d_in[0];
    const float* sat = (const float*)d_in[1];
    float* out = (float*)d_out;
    char* ws = (char*)d_ws;

    float*    normsq   = (float*)(ws + OFF_NORMSQ);
    int*      yx       = (int*)  (ws + OFF_YX);
    float*    partical = (float*)(ws + OFF_PARTICAL);
    float*    corr     = (float*)(ws + OFF_CORR);
    float*    E        = (float*)(ws + OFF_E);
    float*    csumg    = (float*)(ws + OFF_CSUMG);
    _Float16* grdh     = (_Float16*)(ws + OFF_GRDH);
    _Float16* sath     = (_Float16*)(ws + OFF_SATH);
    float*    partials = (float*)(ws + OFF_PARTIALS);

    hipFuncSetAttribute(reinterpret_cast<const void*>(k_gemm),
                        hipFuncAttributeMaxDynamicSharedMemorySize, LDS_TOTAL);

    k_init<<<(CORR_N + 255)/256, 256, 0, stream>>>(corr, normsq);
    k_grdconv<<<dim3(288, 8), 256, 0, stream>>>(grd, grdh, csumg, normsq);
    k_satconv<<<dim3(256, 8), 256, 0, stream>>>(sat, sath, E);
    k_gemm<<<NWG_GEMM, 256, LDS_TOTAL, stream>>>(grdh, sath, partials);
    k_reduce<<<dim3((CORR_N + 255)/256, 8), 256, 0, stream>>>(partials, corr);
    k_part<<<dim3(17, 8), 256, 0, stream>>>(E, partical);
    k_sim<<<64, 64, 0, stream>>>(corr, partical, normsq, out, yx);
    k_mask<<<dim3(256, 8), 256, 0, stream>>>(csumg, normsq, yx, out);
}

// Round 6
// 378.340 us; speedup vs baseline: 1.5975x; 1.1253x over previous
//
#include <hip/hip_runtime.h>

typedef _Float16 half8 __attribute__((ext_vector_type(8)));
typedef _Float16 half4 __attribute__((ext_vector_type(4)));
typedef float floatx4 __attribute__((ext_vector_type(4)));
typedef unsigned short ushort8v __attribute__((ext_vector_type(8)));

#define NS 8
#define CCH 32
#define PADW 272
#define GRDH_ROWS 288
#define CORR_N (136*136)
#define PCOPY (8*32*272*272)             // elems per parity copy (18,939,904)
#define NWG_GEMM 512

#define LDSA_BYTES 81920                 // 160 rows x 256 halfs (XOR-swizzled 16B chunks)
#define LDSB_BYTES 69632                 // 32 superrows x (4 parities x 544 B)
#define LDS_TOTAL  (LDSA_BYTES + LDSB_BYTES)   // 151552 <= 160 KiB

// ---- workspace offsets (bytes) ----
#define OFF_NORMSQ   ((size_t)0)
#define OFF_YX       ((size_t)256)
#define OFF_PARTICAL ((size_t)512)                 // 8*17*17 floats
#define OFF_CORR     ((size_t)10240)               // 136*136 floats
#define OFF_E        ((size_t)0x100000)            // 8*256*256 floats (2 MiB)
#define OFF_CSUMG    ((size_t)0x300000)            // 8*256*256 floats
#define OFF_GRDH     ((size_t)0x500000)            // 8*32*288*256 fp16
#define OFF_SATH     ((size_t)0x2A00000)           // 4 parity copies fp16
#define OFF_PARTIALS ((size_t)0xBB00000)           // 512*136*136 floats

__global__ __launch_bounds__(256) void k_init(float* corr, float* normsq) {
    int t = blockIdx.x * 256 + threadIdx.x;
    if (t < CORR_N) corr[t] = 0.f;
    if (t < 8) normsq[t] = 0.f;
}

// grd -> fp16 padded-row layout + per-sample norm^2 + channel-sum (for mask).
// Thread t: channel cb=t>>5 (4 passes of 8), cols col8..col8+7 -> ushort8 16B stores.
__global__ __launch_bounds__(256) void k_grdconv(const float* __restrict__ grd,
                                                 _Float16* __restrict__ grdh,
                                                 float* __restrict__ csumg,
                                                 float* __restrict__ normsq) {
    int Rg = blockIdx.x;           // 0..287 padded row
    int n  = blockIdx.y;
    int tid = threadIdx.x;
    int cb = tid >> 5;             // 0..7
    int col8 = (tid & 31) * 8;

    if (Rg < 16 || Rg >= 272) {
        ushort8v z = {0,0,0,0,0,0,0,0};
#pragma unroll
        for (int pass = 0; pass < 4; ++pass) {
            int c = pass*8 + cb;
            *(ushort8v*)(grdh + (((size_t)(n*CCH + c))*GRDH_ROWS + Rg)*256 + col8) = z;
        }
        return;
    }
    int i = Rg - 16;
    float ssq = 0.f;
    float cs[8] = {};
    union HU { _Float16 h; unsigned short u; };
#pragma unroll
    for (int pass = 0; pass < 4; ++pass) {
        int c = pass*8 + cb;
        const float* src = grd + (((size_t)(n*CCH + c))*256 + i)*256 + col8;
        float4 v0 = *(const float4*)src;
        float4 v1 = *(const float4*)(src + 4);
        float vv[8] = {v0.x, v0.y, v0.z, v0.w, v1.x, v1.y, v1.z, v1.w};
        ushort8v w;
#pragma unroll
        for (int j = 0; j < 8; ++j) {
            HU hu; hu.h = (_Float16)vv[j]; w[j] = hu.u;
            ssq += vv[j]*vv[j]; cs[j] += vv[j];
        }
        *(ushort8v*)(grdh + (((size_t)(n*CCH + c))*GRDH_ROWS + Rg)*256 + col8) = w;
    }
    __shared__ float sh[8][256];
#pragma unroll
    for (int j = 0; j < 8; ++j) sh[cb][col8 + j] = cs[j];
    __syncthreads();
    float csum = 0.f;
#pragma unroll
    for (int q = 0; q < 8; ++q) csum += sh[q][tid];
    csumg[((size_t)n*256 + i)*256 + tid] = csum;
    for (int o = 32; o; o >>= 1) ssq += __shfl_down(ssq, o, 64);
    if ((tid & 63) == 0) atomicAdd(&normsq[n], ssq);
}

// sat -> 4 parity-shifted fp16 padded copies + per-pixel channel energy E.
// Row staged in LDS once per channel; 136 threads write ushort8 (16B) chunks.
__global__ __launch_bounds__(256) void k_satconv(const float* __restrict__ sat,
                                                 _Float16* __restrict__ sath,
                                                 float* __restrict__ E) {
    int R = blockIdx.x + 8;        // padded row 8..263
    int m = blockIdx.y;
    int tid = threadIdx.x;
    int i = R - 8;
    union HU { _Float16 h; unsigned short u; };

    __shared__ unsigned short lds[280];
    if (tid < 8)  lds[tid] = 0;          // left pad
    if (tid >= 240) lds[tid + 24] = 0;   // 264..279 right pad

    float es = 0.f;
    for (int c = 0; c < CCH; ++c) {
        float v = sat[(((size_t)(m*CCH + c))*256 + i)*256 + tid];
        es += v*v;
        HU h; h.h = (_Float16)v;
        __syncthreads();           // WAR: previous c's readers done
        lds[8 + tid] = h.u;
        __syncthreads();
        if (tid < 136) {
            int p = tid / 34, k = tid - p*34;
            ushort8v w;
#pragma unroll
            for (int j = 0; j < 8; ++j) w[j] = lds[8*k + p + j];
            *(ushort8v*)(sath + (size_t)p*PCOPY +
                         (((size_t)(m*CCH + c))*PADW + R)*PADW + 8*k) = w;
        }
    }
    E[((size_t)m*256 + i)*256 + tid] = es;
}

// all-pairs shifted correlation as MFMA GEMM, LDS-staged via global_load_lds.
// WG = (channel-group of 4) x (band of 4 sat rows); 512 WGs total.
// LDS A: [160 rows][256 halfs], 16B chunks XOR-swizzled by (row & 15).
// LDS B: [32 superrows = 4r x 8m][4 parities x 544 B] -> bank = p*8+q/2+lk*4+ch*16.
__global__ __launch_bounds__(256) void k_gemm(const _Float16* __restrict__ grdh,
                                              const _Float16* __restrict__ sath,
                                              float* __restrict__ partials) {
    extern __shared__ char smem[];
    _Float16* ldsA = (_Float16*)smem;
    _Float16* ldsB = (_Float16*)(smem + LDSA_BYTES);

    const int wgid = blockIdx.x;       // 0..511
    const int cg   = wgid & 7;         // channel group (4 channels each)
    const int band = wgid >> 3;        // 0..63
    const int r0   = 8 + band * 4;
    const int tid  = threadIdx.x;
    const int wave = tid >> 6, lane = tid & 63;
    const int wr = wave >> 1, wc = wave & 1;
    const int lrow = lane & 15, lk = lane >> 4;

    int sBaseA[5];                     // LDS A row base (n*20 + 16 - dy)
    int baseB[5];                      // LDS B byte base
#pragma unroll
    for (int a = 0; a < 5; ++a) {
        int v = (wr*5 + a)*16 + lrow; if (v > 135) v = 135;
        int n = v / 17, dy = v % 17;
        sBaseA[a] = n*20 + 16 - dy;
    }
#pragma unroll
    for (int b = 0; b < 5; ++b) {
        int C = (wc*5 + b)*16 + lrow; if (C > 135) C = 135;
        int m = C / 17, dx = C % 17;
        baseB[b] = m*2176 + (dx & 3)*544 + (((dx & ~3) + lk*8) << 1);
    }

    floatx4 acc[5][5] = {};
    union BU { half8 v; half4 h[2]; };
    half8 A0[5], A1[5];
    BU B0[5], B1[5];

#define LOADPH(Ax, Bx, PH) do { \
    const int r_ = (PH) >> 3, ch_ = (PH) & 7; \
    _Pragma("unroll") for (int a = 0; a < 5; ++a) { \
        int s_ = sBaseA[a] + r_; \
        int byte_ = (s_ << 9) + ((((ch_*4) + lk) ^ (s_ & 15)) << 4); \
        Ax[a] = *(const half8*)((const char*)ldsA + byte_); } \
    _Pragma("unroll") for (int b = 0; b < 5; ++b) { \
        int off_ = baseB[b] + r_*17408 + ch_*64; \
        Bx[b].h[0] = *(const half4*)((const char*)ldsB + off_); \
        Bx[b].h[1] = *(const half4*)((const char*)ldsB + off_ + 8); } \
} while (0)

#define MFMAS(Ax, Bx) do { \
    _Pragma("unroll") for (int a = 0; a < 5; ++a) \
    _Pragma("unroll") for (int b = 0; b < 5; ++b) \
        acc[a][b] = __builtin_amdgcn_mfma_f32_16x16x32_f16(Ax[a], Bx[b].v, acc[a][b], 0, 0, 0); \
} while (0)

    for (int g = 0; g < 4; ++g) {
        int cc = cg*4 + g;
        __syncthreads();               // prev iteration's readers done
        // stage A: 5120 x 16B chunks (20 per thread), XOR(row&15) pre-swizzled source
#pragma unroll
        for (int it = 0; it < 20; ++it) {
            int chunk = it*256 + tid;
            int s = chunk >> 5, k = chunk & 31;
            int n = s / 20, w = s - n*20;
            const _Float16* src = grdh +
                ((((size_t)(n*CCH + cc))*GRDH_ROWS + (r0 + w)) << 8) + ((k ^ (s & 15)) << 3);
            __builtin_amdgcn_global_load_lds(src, ldsA + chunk*8, 16, 0, 0);
        }
        // stage B: 4352 x 16B chunks (17 per thread): superrow (r*8+m) = 4p x 544B
#pragma unroll
        for (int it = 0; it < 17; ++it) {
            int chunk = it*256 + tid;
            int rm = chunk / 136;
            int rest = chunk - rm*136;
            int p = rest / 34, k = rest - p*34;
            const _Float16* src = sath + (size_t)p*PCOPY +
                (((size_t)((rm & 7)*CCH + cc))*PADW + (r0 + (rm >> 3)))*PADW + k*8;
            __builtin_amdgcn_global_load_lds(src, ldsB + chunk*8, 16, 0, 0);
        }
        asm volatile("s_waitcnt vmcnt(0)" ::: "memory");
        __syncthreads();               // all staging visible

        LOADPH(A0, B0, 0);
#pragma unroll
        for (int ph = 0; ph < 32; ++ph) {
            if ((ph & 1) == 0) {
                if (ph < 31) LOADPH(A1, B1, ph + 1);
                MFMAS(A0, B0);
            } else {
                if (ph < 31) LOADPH(A0, B0, ph + 1);
                MFMAS(A1, B1);
            }
        }
    }
#undef LOADPH
#undef MFMAS

    float* myp = partials + (size_t)wgid * CORR_N;
#pragma unroll
    for (int a = 0; a < 5; ++a) {
        int rowb = (wr*5 + a)*16 + lk*4;
#pragma unroll
        for (int b = 0; b < 5; ++b) {
            int colg = (wc*5 + b)*16 + lrow;
            if (colg < 136) {
#pragma unroll
                for (int v = 0; v < 4; ++v) {
                    int rowg = rowb + v;
                    if (rowg < 136) myp[rowg*136 + colg] = acc[a][b][v];
                }
            }
        }
    }
}

__global__ __launch_bounds__(256) void k_reduce(const float* __restrict__ partials,
                                                float* __restrict__ corr) {
    int t = blockIdx.x * 256 + threadIdx.x;
    if (t >= CORR_N) return;
    int w0 = blockIdx.y * 64;
    float s = 0.f;
    for (int w = w0; w < w0 + 64; ++w) s += partials[(size_t)w*CORR_N + t];
    atomicAdd(&corr[t], s);
}

__global__ __launch_bounds__(256) void k_part(const float* __restrict__ E,
                                              float* __restrict__ partical) {
    int dy = blockIdx.x;   // 0..16
    int m  = blockIdx.y;
    int j  = threadIdx.x;
    int lo = dy - 8; if (lo < 0) lo = 0;
    int hi = dy + 248; if (hi > 256) hi = 256;
    float s = 0.f;
    for (int i = lo; i < hi; ++i) s += E[((size_t)m*256 + i)*256 + j];
    __shared__ float sh[256];
    sh[j] = s;
    __syncthreads();
    if (j < 17) {
        int lo2 = j - 8; if (lo2 < 0) lo2 = 0;
        int hi2 = j + 248; if (hi2 > 256) hi2 = 256;
        float t = 0.f;
        for (int x = lo2; x < hi2; ++x) t += sh[x];
        partical[(m*17 + dy)*17 + j] = t;
    }
}

__global__ __launch_bounds__(64) void k_sim(const float* __restrict__ corr,
                                            const float* __restrict__ partical,
                                            const float* __restrict__ normsq,
                                            float* __restrict__ out,
                                            int* __restrict__ yx) {
    int m = blockIdx.x >> 3, n = blockIdx.x & 7;
    int lane = threadIdx.x;
    float Ng = sqrtf(normsq[n]);
    float bv = -1e30f; int bpos = 0;
    for (int t = 0; t < 5; ++t) {
        int pos = t*64 + lane;
        if (pos < 289) {
            int dy = pos / 17, dx = pos % 17;
            float denom = fmaxf(Ng * sqrtf(partical[(m*17 + dy)*17 + dx]), 1e-12f);
            float val = corr[(n*17 + dy)*136 + (m*17 + dx)] / denom;
            if (val > bv) { bv = val; bpos = pos; }  // strict > keeps first index
        }
    }
    for (int o = 32; o; o >>= 1) {
        float ov = __shfl_xor(bv, o, 64);
        int   op = __shfl_xor(bpos, o, 64);
        if (ov > bv || (ov == bv && op < bpos)) { bv = ov; bpos = op; }
    }
    if (lane == 0) {
        out[m*8 + n] = bv;
        if (m == n) yx[m] = bpos;
    }
}

__global__ __launch_bounds__(256) void k_mask(const float* __restrict__ csumg,
                                              const float* __restrict__ normsq,
                                              const int* __restrict__ yx,
                                              float* __restrict__ out) {
    int i = blockIdx.x, m = blockIdx.y, j = threadIdx.x;
    int pos = yx[m];
    int y = pos / 17, x = pos % 17;
    float Ng = sqrtf(normsq[m]);
    int a = i + 8 - y, b = j + 8 - x;
    float val = 0.f;
    if (a >= 0 && a < 256 && b >= 0 && b < 256)
        val = (fabsf(csumg[((size_t)m*256 + a)*256 + b]) > 1e-6f*Ng) ? 1.f : 0.f;
    out[64 + ((size_t)m*256 + i)*256 + j] = val;
}

extern "C" void kernel_launch(void* const* d_in, const int* in_sizes, int n_in,
                              void* d_out, int out_size, void* d_ws, size_t ws_size,
                              hipStream_t stream) {
    const float* grd = (const float*)d_in[0];
    const float* sat = (const float*)d_in[1];
    float* out = (float*)d_out;
    char* ws = (char*)d_ws;

    float*    normsq   = (float*)(ws + OFF_NORMSQ);
    int*      yx       = (int*)  (ws + OFF_YX);
    float*    partical = (float*)(ws + OFF_PARTICAL);
    float*    corr     = (float*)(ws + OFF_CORR);
    float*    E        = (float*)(ws + OFF_E);
    float*    csumg    = (float*)(ws + OFF_CSUMG);
    _Float16* grdh     = (_Float16*)(ws + OFF_GRDH);
    _Float16* sath     = (_Float16*)(ws + OFF_SATH);
    float*    partials = (float*)(ws + OFF_PARTIALS);

    hipFuncSetAttribute(reinterpret_cast<const void*>(k_gemm),
                        hipFuncAttributeMaxDynamicSharedMemorySize, LDS_TOTAL);

    k_init<<<(CORR_N + 255)/256, 256, 0, stream>>>(corr, normsq);
    k_grdconv<<<dim3(288, 8), 256, 0, stream>>>(grd, grdh, csumg, normsq);
    k_satconv<<<dim3(256, 8), 256, 0, stream>>>(sat, sath, E);
    k_gemm<<<NWG_GEMM, 256, LDS_TOTAL, stream>>>(grdh, sath, partials);
    k_reduce<<<dim3((CORR_N + 255)/256, 8), 256, 0, stream>>>(partials, corr);
    k_part<<<dim3(17, 8), 256, 0, stream>>>(E, partical);
    k_sim<<<64, 64, 0, stream>>>(corr, partical, normsq, out, yx);
    k_mask<<<dim3(256, 8), 256, 0, stream>>>(csumg, normsq, yx, out);
}

// Round 9
// 350.435 us; speedup vs baseline: 1.7247x; 1.0796x over previous
//
#include <hip/hip_runtime.h>

typedef _Float16 half8 __attribute__((ext_vector_type(8)));
typedef float floatx4 __attribute__((ext_vector_type(4)));
typedef unsigned short ushort8v __attribute__((ext_vector_type(8)));

#define NS 8
#define CCH 32
#define PADW 272
#define GRDH_ROWS 288
#define CORR_N (136*136)
#define PCOPY2 ((size_t)(8*32*272*288))  // elems per parity copy (20,054,016)
#define NWG_GEMM 1024

#define LDSA_BYTES 40960                 // 80 rows x 256 halfs (XOR-swizzled 16B chunks)
#define LDSB_BYTES 36864                 // 32 superrows x 1152 B (2 parities x 576), NO pad:
                                         // global_load_lds dest must be linear in chunk!
#define LDS_TOTAL  (LDSA_BYTES + LDSB_BYTES)   // 77824 -> 2 WG/CU

// ---- workspace offsets (bytes) ----
#define OFF_NORMSQ   ((size_t)0)
#define OFF_YX       ((size_t)256)
#define OFF_PARTICAL ((size_t)512)                 // 8*17*17 floats
#define OFF_CORR     ((size_t)10240)               // 136*136 floats
#define OFF_E        ((size_t)0x100000)            // 8*256*256 floats (2 MiB)
#define OFF_CSUMG    ((size_t)0x300000)            // 8*256*256 floats
#define OFF_GRDH     ((size_t)0x500000)            // 8*32*288*256 fp16
#define OFF_SATH     ((size_t)0x2A00000)           // 2 parity copies fp16 (80.2 MB)
#define OFF_PARTIALS ((size_t)0xBB00000)           // 512*136*136 floats

__global__ __launch_bounds__(256) void k_init(float* corr, float* normsq) {
    int t = blockIdx.x * 256 + threadIdx.x;
    if (t < CORR_N) corr[t] = 0.f;
    if (t < 8) normsq[t] = 0.f;
}

// grd -> fp16 padded-row layout + per-sample norm^2 + channel-sum (for mask).
__global__ __launch_bounds__(256) void k_grdconv(const float* __restrict__ grd,
                                                 _Float16* __restrict__ grdh,
                                                 float* __restrict__ csumg,
                                                 float* __restrict__ normsq) {
    int Rg = blockIdx.x;           // 0..287 padded row
    int n  = blockIdx.y;
    int tid = threadIdx.x;
    int cb = tid >> 5;             // 0..7
    int col8 = (tid & 31) * 8;

    if (Rg < 16 || Rg >= 272) {
        ushort8v z = {0,0,0,0,0,0,0,0};
#pragma unroll
        for (int pass = 0; pass < 4; ++pass) {
            int c = pass*8 + cb;
            *(ushort8v*)(grdh + (((size_t)(n*CCH + c))*GRDH_ROWS + Rg)*256 + col8) = z;
        }
        return;
    }
    int i = Rg - 16;
    float ssq = 0.f;
    float cs[8] = {};
    union HU { _Float16 h; unsigned short u; };
#pragma unroll
    for (int pass = 0; pass < 4; ++pass) {
        int c = pass*8 + cb;
        const float* src = grd + (((size_t)(n*CCH + c))*256 + i)*256 + col8;
        float4 v0 = *(const float4*)src;
        float4 v1 = *(const float4*)(src + 4);
        float vv[8] = {v0.x, v0.y, v0.z, v0.w, v1.x, v1.y, v1.z, v1.w};
        ushort8v w;
#pragma unroll
        for (int j = 0; j < 8; ++j) {
            HU hu; hu.h = (_Float16)vv[j]; w[j] = hu.u;
            ssq += vv[j]*vv[j]; cs[j] += vv[j];
        }
        *(ushort8v*)(grdh + (((size_t)(n*CCH + c))*GRDH_ROWS + Rg)*256 + col8) = w;
    }
    __shared__ float sh[8][256];
#pragma unroll
    for (int j = 0; j < 8; ++j) sh[cb][col8 + j] = cs[j];
    __syncthreads();
    float csum = 0.f;
#pragma unroll
    for (int q = 0; q < 8; ++q) csum += sh[q][tid];
    csumg[((size_t)n*256 + i)*256 + tid] = csum;
    for (int o = 32; o; o >>= 1) ssq += __shfl_down(ssq, o, 64);
    if ((tid & 63) == 0) atomicAdd(&normsq[n], ssq);
}

// sat -> 2 parity-shifted fp16 padded copies (copy p, in-row index q holds satpad[q+p])
// + per-pixel channel energy E. All 32 channel loads issued up-front.
__global__ __launch_bounds__(256) void k_satconv(const float* __restrict__ sat,
                                                 _Float16* __restrict__ satp,
                                                 float* __restrict__ E) {
    int R = blockIdx.x + 8;        // padded row 8..263
    int m = blockIdx.y;
    int tid = threadIdx.x;
    int i = R - 8;
    union HU { _Float16 h; unsigned short u; };

    __shared__ unsigned short lds[296];
    if (tid < 8)  lds[tid] = 0;          // left pad
    if (tid >= 224) lds[tid + 40] = 0;   // 264..295 right pad

    float vreg[32];
#pragma unroll
    for (int c = 0; c < CCH; ++c)
        vreg[c] = sat[(((size_t)(m*CCH + c))*256 + i)*256 + tid];

    float es = 0.f;
#pragma unroll
    for (int c = 0; c < CCH; ++c) es += vreg[c]*vreg[c];
    E[((size_t)m*256 + i)*256 + tid] = es;

    int p = (tid >= 36) ? 1 : 0;   // for tid < 72
    int k = tid - p*36;
#pragma unroll
    for (int c = 0; c < CCH; ++c) {
        HU h; h.h = (_Float16)vreg[c];
        __syncthreads();           // WAR: previous c's readers done
        lds[8 + tid] = h.u;
        __syncthreads();
        if (tid < 72) {
            ushort8v w;
#pragma unroll
            for (int j = 0; j < 8; ++j) w[j] = lds[8*k + p + j];
            *(ushort8v*)(satp + (size_t)p*PCOPY2 +
                         (((size_t)(m*CCH + c))*272 + R)*288 + 8*k) = w;
        }
    }
}

// all-pairs shifted correlation as MFMA GEMM, LDS-staged via global_load_lds.
// WG = 128 threads (2 waves), 4n x 8m, band of 4 sat rows, 4 channels staged serially.
// 1024 WGs; LDS 77.8 KB -> 2 WG/CU co-resident (stage/compute overlap across WGs).
// LDS A: [80 rows][256 halfs], 16B chunks XOR-swizzled by (row & 15).
// LDS B: [32 superrows = 4r x 8m][2 parities x 576 B], stride 1152 (dest linear in chunk;
//        banks: 288*m==0 mod 32, p*16+q/2 distinct over 16 lanes -> ~2-way, free).
__global__ __launch_bounds__(128, 1) void k_gemm(const _Float16* __restrict__ grdh,
                                                 const _Float16* __restrict__ satp,
                                                 float* __restrict__ partials) {
    extern __shared__ char smem[];
    _Float16* ldsA = (_Float16*)smem;
    char*     ldsB = smem + LDSA_BYTES;

    const int wgid = blockIdx.x;        // 0..1023
    const int band = wgid >> 4;         // 0..63
    const int cg   = (wgid >> 1) & 7;   // channel group (4 channels)
    const int nh   = wgid & 1;          // n half: n = nh*4 + n'
    const int r0   = 8 + band * 4;
    const int tid  = threadIdx.x;       // 0..127
    const int wc   = tid >> 6;          // wave = column half
    const int lane = tid & 63;
    const int lrow = lane & 15, lk = lane >> 4;

    int sBaseA[5];                      // LDS A row base (n'*20 + 16 - dy)
    int baseB[5];                       // LDS B byte base
#pragma unroll
    for (int a = 0; a < 5; ++a) {
        int v = a*16 + lrow; if (v > 67) v = 67;
        int n = v / 17, dy = v % 17;
        sBaseA[a] = n*20 + 16 - dy;
    }
#pragma unroll
    for (int b = 0; b < 5; ++b) {
        int C = (wc*5 + b)*16 + lrow; if (C > 135) C = 135;
        int m = C / 17, dx = C % 17;
        int p = dx & 1, q = dx & ~1;
        baseB[b] = m*1152 + p*576 + ((q + lk*8) << 1);
    }

    floatx4 acc[5][5] = {};
    half8 A0[5], A1[5], B0[5], B1[5];

#define LOADPH(Ax, Bx, PH) do { \
    const int r_ = (PH) >> 3, ch_ = (PH) & 7; \
    _Pragma("unroll") for (int a = 0; a < 5; ++a) { \
        int s_ = sBaseA[a] + r_; \
        int byte_ = (s_ << 9) + ((((ch_*4) + lk) ^ (s_ & 15)) << 4); \
        Ax[a] = *(const half8*)((const char*)ldsA + byte_); } \
    _Pragma("unroll") for (int b = 0; b < 5; ++b) { \
        int off_ = baseB[b] + r_*9216 + ch_*64; \
        union { unsigned u[4]; half8 v; } U_; \
        U_.u[0] = *(const unsigned*)(ldsB + off_); \
        U_.u[1] = *(const unsigned*)(ldsB + off_ + 4); \
        U_.u[2] = *(const unsigned*)(ldsB + off_ + 8); \
        U_.u[3] = *(const unsigned*)(ldsB + off_ + 12); \
        Bx[b] = U_.v; } \
} while (0)

#define MFMAS(Ax, Bx) do { \
    _Pragma("unroll") for (int a = 0; a < 5; ++a) \
    _Pragma("unroll") for (int b = 0; b < 5; ++b) \
        acc[a][b] = __builtin_amdgcn_mfma_f32_16x16x32_f16(Ax[a], Bx[b], acc[a][b], 0, 0, 0); \
} while (0)

    for (int g = 0; g < 4; ++g) {
        int cc = cg*4 + g;
        __syncthreads();               // prev iteration's readers done
        // stage A: 2560 x 16B chunks (20/thread), XOR(row&15) pre-swizzled source
#pragma unroll
        for (int it = 0; it < 20; ++it) {
            int chunk = it*128 + tid;
            int s = chunk >> 5, k = chunk & 31;
            int n = s / 20, w = s - n*20;
            const _Float16* src = grdh +
                ((((size_t)((nh*4 + n)*CCH + cc))*GRDH_ROWS + (r0 + w)) << 8) +
                ((k ^ (s & 15)) << 3);
            __builtin_amdgcn_global_load_lds(src, ldsA + chunk*8, 16, 0, 0);
        }
        // stage B: 2304 x 16B chunks (18/thread): superrow (r*8+m) = 2p x 576B, linear
#pragma unroll
        for (int it = 0; it < 18; ++it) {
            int chunk = it*128 + tid;
            int sr = chunk / 72;
            int rest = chunk - sr*72;
            int p = (rest >= 36) ? 1 : 0;
            int k = rest - p*36;
            const _Float16* src = satp + (size_t)p*PCOPY2 +
                (((size_t)((sr & 7)*CCH + cc))*272 + (r0 + (sr >> 3)))*288 + k*8;
            __builtin_amdgcn_global_load_lds(src,
                (_Float16*)(ldsB + chunk*16), 16, 0, 0);
        }
        asm volatile("s_waitcnt vmcnt(0)" ::: "memory");
        __syncthreads();               // all staging visible

        LOADPH(A0, B0, 0);
#pragma unroll
        for (int ph = 0; ph < 32; ++ph) {
            if ((ph & 1) == 0) {
                if (ph < 31) LOADPH(A1, B1, ph + 1);
                MFMAS(A0, B0);
            } else {
                if (ph < 31) LOADPH(A0, B0, ph + 1);
                MFMAS(A1, B1);
            }
        }
    }
#undef LOADPH
#undef MFMAS

    // n-half WGs share slice (band*8+cg) but write disjoint row ranges.
    float* myp = partials + (size_t)(band*8 + cg) * CORR_N;
#pragma unroll
    for (int a = 0; a < 5; ++a) {
#pragma unroll
        for (int b = 0; b < 5; ++b) {
            int colg = (wc*5 + b)*16 + lrow;
            if (colg < 136) {
#pragma unroll
                for (int v = 0; v < 4; ++v) {
                    int vloc = a*16 + lk*4 + v;
                    if (vloc < 68) myp[(nh*68 + vloc)*136 + colg] = acc[a][b][v];
                }
            }
        }
    }
}

__global__ __launch_bounds__(256) void k_reduce(const float* __restrict__ partials,
                                                float* __restrict__ corr) {
    int t = blockIdx.x * 256 + threadIdx.x;
    if (t >= CORR_N) return;
    int w0 = blockIdx.y * 64;
    float s = 0.f;
    for (int w = w0; w < w0 + 64; ++w) s += partials[(size_t)w*CORR_N + t];
    atomicAdd(&corr[t], s);
}

__global__ __launch_bounds__(256) void k_part(const float* __restrict__ E,
                                              float* __restrict__ partical) {
    int dy = blockIdx.x;   // 0..16
    int m  = blockIdx.y;
    int j  = threadIdx.x;
    int lo = dy - 8; if (lo < 0) lo = 0;
    int hi = dy + 248; if (hi > 256) hi = 256;
    float s = 0.f;
    for (int i = lo; i < hi; ++i) s += E[((size_t)m*256 + i)*256 + j];
    __shared__ float sh[256];
    sh[j] = s;
    __syncthreads();
    if (j < 17) {
        int lo2 = j - 8; if (lo2 < 0) lo2 = 0;
        int hi2 = j + 248; if (hi2 > 256) hi2 = 256;
        float t = 0.f;
        for (int x = lo2; x < hi2; ++x) t += sh[x];
        partical[(m*17 + dy)*17 + j] = t;
    }
}

__global__ __launch_bounds__(64) void k_sim(const float* __restrict__ corr,
                                            const float* __restrict__ partical,
                                            const float* __restrict__ normsq,
                                            float* __restrict__ out,
                                            int* __restrict__ yx) {
    int m = blockIdx.x >> 3, n = blockIdx.x & 7;
    int lane = threadIdx.x;
    float Ng = sqrtf(normsq[n]);
    float bv = -1e30f; int bpos = 0;
    for (int t = 0; t < 5; ++t) {
        int pos = t*64 + lane;
        if (pos < 289) {
            int dy = pos / 17, dx = pos % 17;
            float denom = fmaxf(Ng * sqrtf(partical[(m*17 + dy)*17 + dx]), 1e-12f);
            float val = corr[(n*17 + dy)*136 + (m*17 + dx)] / denom;
            if (val > bv) { bv = val; bpos = pos; }  // strict > keeps first index
        }
    }
    for (int o = 32; o; o >>= 1) {
        float ov = __shfl_xor(bv, o, 64);
        int   op = __shfl_xor(bpos, o, 64);
        if (ov > bv || (ov == bv && op < bpos)) { bv = ov; bpos = op; }
    }
    if (lane == 0) {
        out[m*8 + n] = bv;
        if (m == n) yx[m] = bpos;
    }
}

__global__ __launch_bounds__(256) void k_mask(const float* __restrict__ csumg,
                                              const float* __restrict__ normsq,
                                              const int* __restrict__ yx,
                                              float* __restrict__ out) {
    int i = blockIdx.x, m = blockIdx.y, j = threadIdx.x;
    int pos = yx[m];
    int y = pos / 17, x = pos % 17;
    float Ng = sqrtf(normsq[m]);
    int a = i + 8 - y, b = j + 8 - x;
    float val = 0.f;
    if (a >= 0 && a < 256 && b >= 0 && b < 256)
        val = (fabsf(csumg[((size_t)m*256 + a)*256 + b]) > 1e-6f*Ng) ? 1.f : 0.f;
    out[64 + ((size_t)m*256 + i)*256 + j] = val;
}

extern "C" void kernel_launch(void* const* d_in, const int* in_sizes, int n_in,
                              void* d_out, int out_size, void* d_ws, size_t ws_size,
                              hipStream_t stream) {
    const float* grd = (const float*)d_in[0];
    const float* sat = (const float*)d_in[1];
    float* out = (float*)d_out;
    char* ws = (char*)d_ws;

    float*    normsq   = (float*)(ws + OFF_NORMSQ);
    int*      yx       = (int*)  (ws + OFF_YX);
    float*    partical = (float*)(ws + OFF_PARTICAL);
    float*    corr     = (float*)(ws + OFF_CORR);
    float*    E        = (float*)(ws + OFF_E);
    float*    csumg    = (float*)(ws + OFF_CSUMG);
    _Float16* grdh     = (_Float16*)(ws + OFF_GRDH);
    _Float16* satp     = (_Float16*)(ws + OFF_SATH);
    float*    partials = (float*)(ws + OFF_PARTIALS);

    hipFuncSetAttribute(reinterpret_cast<const void*>(k_gemm),
                        hipFuncAttributeMaxDynamicSharedMemorySize, LDS_TOTAL);

    k_init<<<(CORR_N + 255)/256, 256, 0, stream>>>(corr, normsq);
    k_grdconv<<<dim3(288, 8), 256, 0, stream>>>(grd, grdh, csumg, normsq);
    k_satconv<<<dim3(256, 8), 256, 0, stream>>>(sat, satp, E);
    k_gemm<<<NWG_GEMM, 128, LDS_TOTAL, stream>>>(grdh, satp, partials);
    k_reduce<<<dim3((CORR_N + 255)/256, 8), 256, 0, stream>>>(partials, corr);
    k_part<<<dim3(17, 8), 256, 0, stream>>>(E, partical);
    k_sim<<<64, 64, 0, stream>>>(corr, partical, normsq, out, yx);
    k_mask<<<dim3(256, 8), 256, 0, stream>>>(csumg, normsq, yx, out);
}